// Round 4
// baseline (19.739 us; speedup 1.0000x reference)
//
#include <hip/hip_runtime.h>

#define NS 32
#define NH 32
#define C2L 2.8853900817779268f  // 2*log2(e): e^(2x) = 2^(C2L*x)

// 4 threads per point; thread j handles segment s0+j (the only <=4 segments
// with nonzero cosine window). Weights packed in LDS as float4 [hchunk][s]:
// per-lane segment gathers use ds_read_b128, 24 reads per wave per h-loop.
// Staging uses s-fast thread decode so LDS writes are conflict-free.
__global__ __launch_bounds__(256, 4) void springnn_kernel(
    const float* __restrict__ t_in,
    const float* __restrict__ W1,   // [S][1][H]
    const float* __restrict__ b1,   // [S][H]
    const float* __restrict__ W2,   // [S][H][1]
    const float* __restrict__ b2,   // [S][1]
    float* __restrict__ out,
    int N)
{
    __shared__ float4 w1b1p[NH / 2][NS]; // [h2][s] = (w1[2h2],b1[2h2],w1[2h2+1],b1[2h2+1])*C2L
    __shared__ float4 w2p[NH / 4][NS];   // [h4][s] = -2*W2[s][4h4..4h4+3]
    __shared__ float  b2eff[NS];         // b2[s] + sum_h W2[s][h]  (tanh folding)

    const int tid = threadIdx.x;

    // ---- stage weights into LDS; s is the fast (lane) index -> conflict-free ----
    #pragma unroll
    for (int it = 0; it < 4; ++it) {
        const int idx = it * 256 + tid;
        const int s = idx & (NS - 1);
        const int h = idx >> 5;
        const float w1v = W1[s * NH + h] * C2L;
        const float b1v = b1[s * NH + h] * C2L;
        ((float2*)&w1b1p[h >> 1][s])[h & 1] = make_float2(w1v, b1v);
        ((float*)&w2p[h >> 2][s])[h & 3] = -2.0f * W2[s * NH + h];
    }
    if (tid < NS) {
        float acc = b2[tid];
        const float4* w2v = (const float4*)(W2 + tid * NH);
        #pragma unroll
        for (int q = 0; q < NH / 4; ++q) {
            float4 v = w2v[q];
            acc += (v.x + v.y) + (v.z + v.w);
        }
        b2eff[tid] = acc;
    }
    __syncthreads();

    const int gid = blockIdx.x * 256 + tid;
    const int n = gid >> 2;          // point index
    const int j = tid & 3;           // segment slot 0..3
    if (n >= N) return;
    const float t = t_in[n];

    // s0 = ceil(t-2): d_j = t-(s0+j) spans (1,2],(0,1],(-1,0],(-2,-1] for j=0..3;
    // j=4 would give d<=-2 where the window is exactly 0, so 4 slots suffice.
    const int s = (int)ceilf(t - 2.0f) + j;

    float val = 0.0f;
    if (s >= 0 && s < NS) {
        // window = (1+cos(pi*d/2))/2 = cos^2(pi*d/4); v_cos takes revolutions
        const float c = __builtin_amdgcn_cosf((t - (float)s) * 0.125f);

        float o0 = b2eff[s], o1 = 0.0f, o2 = 0.0f, o3 = 0.0f;  // 4 chains for ILP
        #pragma unroll
        for (int h4 = 0; h4 < NH / 4; ++h4) {
            const float4 wq = w2p[h4][s];
            const float4 a = w1b1p[2 * h4][s];
            const float4 b = w1b1p[2 * h4 + 1][s];
            const float e0 = __builtin_amdgcn_exp2f(fmaf(t, a.x, a.y));
            const float e1 = __builtin_amdgcn_exp2f(fmaf(t, a.z, a.w));
            const float e2 = __builtin_amdgcn_exp2f(fmaf(t, b.x, b.y));
            const float e3 = __builtin_amdgcn_exp2f(fmaf(t, b.z, b.w));
            o0 = fmaf(wq.x, __builtin_amdgcn_rcpf(e0 + 1.0f), o0);
            o1 = fmaf(wq.y, __builtin_amdgcn_rcpf(e1 + 1.0f), o1);
            o2 = fmaf(wq.z, __builtin_amdgcn_rcpf(e2 + 1.0f), o2);
            o3 = fmaf(wq.w, __builtin_amdgcn_rcpf(e3 + 1.0f), o3);
        }
        val = c * c * ((o0 + o1) + (o2 + o3));
    }

    // sum the 4 segment partials (lanes j=0..3 within an aligned 4-lane group)
    val += __shfl_xor(val, 1, 64);
    val += __shfl_xor(val, 2, 64);
    if (j == 0) out[n] = val;
}

extern "C" void kernel_launch(void* const* d_in, const int* in_sizes, int n_in,
                              void* d_out, int out_size, void* d_ws, size_t ws_size,
                              hipStream_t stream) {
    const float* t  = (const float*)d_in[0];
    const float* W1 = (const float*)d_in[1];
    const float* b1 = (const float*)d_in[2];
    const float* W2 = (const float*)d_in[3];
    const float* b2 = (const float*)d_in[4];
    float* outp = (float*)d_out;
    const int N = in_sizes[0];

    const int block = 256;
    const long long threads = (long long)N * 4;
    const int grid = (int)((threads + block - 1) / block);
    springnn_kernel<<<grid, block, 0, stream>>>(t, W1, b1, W2, b2, outp, N);
}